// Round 7
// baseline (33.256 us; speedup 1.0000x reference)
//
#include <hip/hip_runtime.h>
#include <math.h>

#define KNN 8
#define QPB 8           // queries per block
#define SUB 32          // sub-lanes per query
#define BLK 256         // QPB*SUB threads, 4 waves
#define CAP 1024        // staged candidates per LDS tile

__device__ __forceinline__ int lbound_g(const int* __restrict__ a, int n, int v) {
  int lo = 0, hi = n;
  while (lo < hi) { int m = (lo + hi) >> 1; if (a[m] < v) lo = m + 1; else hi = m; }
  return lo;
}

// Fused select+gather. Per block: wave-cooperative range search -> stage
// coords in LDS -> 32-way sliced top-8 scan -> merged extraction where each
// merge round's winner (converged in all 32 lanes by the shfl butterfly)
// immediately issues its feature-gather loads (merge latency hides gather
// latency). Lane l handles dims (l&31)+{0,32,64,96} of its own query.
// One deterministic partial per block. No fences, no atomics.
__launch_bounds__(BLK, 8)
__global__ void knn_fused(const float* __restrict__ x1,
                          const float* __restrict__ x2,
                          const int* __restrict__ b1,
                          const int* __restrict__ b2,
                          int N, int ROW,
                          float* __restrict__ ws_part) {
  __shared__ float4 c4[CAP];          // {x, y, z, |c|^2}
  __shared__ int   s_info[4];         // {s1, e1, b_first, b_last}
  __shared__ float wred[BLK / 64];

  const int tid  = threadIdx.x;
  const int lane = tid & 63;
  const int wv   = tid >> 6;          // 0..3
  const int qi   = tid >> 5;          // query within block (SUB=32)
  const int sub  = tid & (SUB - 1);
  const int dl   = lane & 31;         // owned feature dim base
  const int q0   = blockIdx.x * QPB;
  const int q    = q0 + qi;
  const int qlast = min(q0 + QPB - 1, N - 1);

  // Wave-cooperative lower_bound on b1 (64-way fanout, ~3 dependent rounds).
  if (wv < 2) {
    const int bb = (wv == 0) ? b2[q0] : b2[qlast];
    const int target = bb + wv;       // wv0: lb(b_first), wv1: lb(b_last+1)
    int lo = 0, hi = N;
    while (lo < hi) {
      int step = (hi - lo + 63) >> 6;
      int p = lo + lane * step;
      bool pred = (p < hi) && (b1[p] < target);
      int c = __popcll(__ballot(pred));
      if (c == 0) { hi = lo; break; }
      int nlo = lo + (c - 1) * step + 1;
      hi = min(hi, lo + c * step);
      lo = nlo;
    }
    if (lane == 0) { s_info[wv] = lo; s_info[2 + wv] = bb; }
  }

  // Query coords + own-dim x2 features (independent of the search).
  float qx = 0.f, qy = 0.f, qz = 0.f; int mybatch = -1;
  float f2v0 = 0.f, f2v1 = 0.f, f2v2 = 0.f, f2v3 = 0.f;
  if (q < N) {
    const float* c2 = x2 + (size_t)q * ROW;
    qx = c2[0]; qy = c2[1]; qz = c2[2];
    mybatch = b2[q];
    const float* f2 = c2 + 3 + dl;
    f2v0 = f2[0]; f2v1 = f2[32]; f2v2 = f2[64]; f2v3 = f2[96];
  }
  const float n2 = qx * qx + qy * qy + qz * qz;

  float dist[KNN]; int nidx[KNN];
#pragma unroll
  for (int k = 0; k < KNN; ++k) { dist[k] = INFINITY; nidx[k] = 0; }

  __syncthreads();
  const int s1 = s_info[0], e1 = s_info[1];
  const bool single = (s_info[2] == s_info[3]);   // block spans one batch

  int qs = s1, qe = e1;
  if (!single && q < N) {             // rare straddle block: per-query range
    qs = lbound_g(b1, N, mybatch);    // (b1 lines are L2-hot from the search)
    qe = lbound_g(b1, N, mybatch + 1);
  }
  if (q >= N) { qs = 0; qe = 0; }

  for (int t0 = s1; t0 < e1; t0 += CAP) {
    const int t1 = min(t0 + CAP, e1);
    __syncthreads();                   // c4 reuse guard (no-op first tile)
    for (int i = t0 + tid; i < t1; i += BLK) {
      const float* p = x1 + (size_t)i * ROW;
      float cx = p[0], cy = p[1], cz = p[2];
      c4[i - t0] = make_float4(cx, cy, cz, cx * cx + cy * cy + cz * cz);
    }
    __syncthreads();
    const int lo = max(qs, t0), hi = min(qe, t1);
    for (int j = lo + sub; j < hi; j += SUB) {
      float4 c = c4[j - t0];
      float d = fmaf(-2.0f, fmaf(qx, c.x, fmaf(qy, c.y, qz * c.z)), n2 + c.w);
      d = fmaxf(d, 0.0f);
      // strict < : ascending j => ties keep earlier index within a slice
      if (d < dist[KNN - 1]) {
        dist[KNN - 1] = d; nidx[KNN - 1] = j;
#pragma unroll
        for (int k = KNN - 1; k > 0; --k) {
          if (dist[k] < dist[k - 1]) {
            float td = dist[k]; dist[k] = dist[k - 1]; dist[k - 1] = td;
            int ti = nidx[k]; nidx[k] = nidx[k - 1]; nidx[k - 1] = ti;
          }
        }
      }
    }
  }

  // Fused exact merge + gather. Round r extracts the lexicographic (d, idx)
  // min across the 32-lane group (butterfly => converged in every lane),
  // then immediately accumulates that neighbor's features for this lane's
  // 4 owned dims. Padded (inf,0) entries contribute w=0 * x1-row-0 = 0.
  float acc0 = 0.f, acc1 = 0.f, acc2 = 0.f, acc3 = 0.f, sw = 0.f;
#pragma unroll
  for (int r = 0; r < KNN; ++r) {
    float hd = dist[0]; int hidx = nidx[0];
    float bd = hd; int bi = hidx;
#pragma unroll
    for (int m = 1; m <= 16; m <<= 1) {
      float od = __shfl_xor(bd, m); int oi = __shfl_xor(bi, m);
      if (od < bd || (od == bd && oi < bi)) { bd = od; bi = oi; }
    }
    if (hd == bd && hidx == bi) {   // pop winner (unique for real entries)
#pragma unroll
      for (int k = 0; k < KNN - 1; ++k) { dist[k] = dist[k + 1]; nidx[k] = nidx[k + 1]; }
      dist[KNN - 1] = INFINITY; nidx[KNN - 1] = 0;
    }
    float w = 1.0f / fmaxf(bd, 1e-16f);   // d=inf (pad) -> w = 0
    sw += w;
    const float* f = x1 + (size_t)bi * ROW + 3 + dl;
    acc0 += w * f[0];
    acc1 += w * f[32];
    acc2 += w * f[64];
    acc3 += w * f[96];
  }

  float pacc = 0.0f;
  if (q < N) {
    float rinv = 1.0f / sw;
    float e0 = acc0 * rinv - f2v0;
    float e1 = acc1 * rinv - f2v1;
    float e2 = acc2 * rinv - f2v2;
    float e3 = acc3 * rinv - f2v3;
    pacc = (e0 * e0 + e1 * e1) + (e2 * e2 + e3 * e3);
  }
#pragma unroll
  for (int off = 32; off > 0; off >>= 1) pacc += __shfl_xor(pacc, off);
  if (lane == 0) wred[wv] = pacc;
  __syncthreads();
  if (tid == 0) {
    float s = (wred[0] + wred[1]) + (wred[2] + wred[3]);
    ws_part[blockIdx.x] = s;
  }
}

// Deterministic final reduction + mean scale.
__global__ void knn_final(const float* __restrict__ part, int n,
                          float scale, float* __restrict__ out) {
  __shared__ float sm[256];
  float s = 0.0f;
  for (int i = threadIdx.x; i < n; i += 256) s += part[i];
  sm[threadIdx.x] = s;
  __syncthreads();
  for (int step = 128; step > 0; step >>= 1) {
    if (threadIdx.x < step) sm[threadIdx.x] += sm[threadIdx.x + step];
    __syncthreads();
  }
  if (threadIdx.x == 0) out[0] = sm[0] * scale;
}

extern "C" void kernel_launch(void* const* d_in, const int* in_sizes, int n_in,
                              void* d_out, int out_size, void* d_ws, size_t ws_size,
                              hipStream_t stream) {
  const float* x1 = (const float*)d_in[0];
  const float* x2 = (const float*)d_in[1];
  const int* b1 = (const int*)d_in[2];
  const int* b2 = (const int*)d_in[3];
  int N = in_sizes[2];            // 16384
  int ROW = in_sizes[0] / N;      // 131
  float* out = (float*)d_out;

  int blocks = (N + QPB - 1) / QPB;              // 2048
  float* ws_part = (float*)d_ws;
  if (ws_size < (size_t)blocks * sizeof(float)) return;

  knn_fused<<<blocks, BLK, 0, stream>>>(x1, x2, b1, b2, N, ROW, ws_part);
  float scale = 1.0f / ((float)N * (float)(ROW - 3));
  knn_final<<<1, 256, 0, stream>>>(ws_part, blocks, scale, out);
}